// Round 4
// baseline (349.153 us; speedup 1.0000x reference)
//
#include <hip/hip_runtime.h>
#include <hip/hip_bf16.h>

// BinaryMoSLinear: B=4, S=2048 -> N=8192 rows; H=O=4096; E=4.
#define H_DIM 4096
#define O_DIM 4096
#define N_ROWS 8192

typedef __bf16 bf16x8 __attribute__((ext_vector_type(8)));
typedef float  f32x4  __attribute__((ext_vector_type(4)));

__device__ __forceinline__ unsigned short f32_bf16_rne(float f) {
    unsigned int u = __builtin_bit_cast(unsigned int, f);
    u += 0x7FFFu + ((u >> 16) & 1u);
    return (unsigned short)(u >> 16);
}

__device__ __forceinline__ void gload_lds16(const unsigned short* g, unsigned short* l) {
    __builtin_amdgcn_global_load_lds((const __attribute__((address_space(1))) void*)g,
                                     (__attribute__((address_space(3))) void*)l,
                                     16, 0, 0);
}

// ---------------------------------------------------------------------------
// Kernel 1: bw = sign(weight) as bf16 (+1.0 / -1.0 / 0.0).
// ---------------------------------------------------------------------------
__global__ void __launch_bounds__(256) sign_kernel(const float* __restrict__ w,
                                                   unsigned short* __restrict__ bw) {
    size_t i = ((size_t)blockIdx.x * 256 + threadIdx.x) * 4;
    float4 v = *reinterpret_cast<const float4*>(w + i);
    ushort4 o;
    o.x = v.x > 0.f ? 0x3F80 : (v.x < 0.f ? 0xBF80 : 0);
    o.y = v.y > 0.f ? 0x3F80 : (v.y < 0.f ? 0xBF80 : 0);
    o.z = v.z > 0.f ? 0x3F80 : (v.z < 0.f ? 0xBF80 : 0);
    o.w = v.w > 0.f ? 0x3F80 : (v.w < 0.f ? 0xBF80 : 0);
    *reinterpret_cast<ushort4*>(bw + i) = o;
}

// ---------------------------------------------------------------------------
// Kernel 2: router softmax -> rw[n][4]; xs = bf16(x * (rw @ in_channel_scale)).
// ---------------------------------------------------------------------------
__global__ void __launch_bounds__(256) route_scale_kernel(
    const float* __restrict__ x, const float* __restrict__ gate_w,
    const float* __restrict__ ics, float* __restrict__ rw_out,
    unsigned short* __restrict__ xs_out)
{
    __shared__ float red[4][4];
    const int n = blockIdx.x;
    const int t = threadIdx.x;
    const float* xr = x + (size_t)n * H_DIM;

    float4 xv[4];
    float lg[4] = {0.f, 0.f, 0.f, 0.f};
#pragma unroll
    for (int c = 0; c < 4; ++c) {
        const int idx = c * 1024 + t * 4;
        xv[c] = *reinterpret_cast<const float4*>(xr + idx);
#pragma unroll
        for (int e = 0; e < 4; ++e) {
            float4 g = *reinterpret_cast<const float4*>(gate_w + e * H_DIM + idx);
            lg[e] += xv[c].x * g.x + xv[c].y * g.y + xv[c].z * g.z + xv[c].w * g.w;
        }
    }
#pragma unroll
    for (int e = 0; e < 4; ++e) {
#pragma unroll
        for (int off = 1; off < 64; off <<= 1)
            lg[e] += __shfl_xor(lg[e], off, 64);
    }
    if ((t & 63) == 0) {
        const int w = t >> 6;
        red[w][0] = lg[0]; red[w][1] = lg[1]; red[w][2] = lg[2]; red[w][3] = lg[3];
    }
    __syncthreads();
    const float l0 = red[0][0] + red[1][0] + red[2][0] + red[3][0];
    const float l1 = red[0][1] + red[1][1] + red[2][1] + red[3][1];
    const float l2 = red[0][2] + red[1][2] + red[2][2] + red[3][2];
    const float l3 = red[0][3] + red[1][3] + red[2][3] + red[3][3];
    const float m  = fmaxf(fmaxf(l0, l1), fmaxf(l2, l3));
    const float p0 = expf(l0 - m), p1 = expf(l1 - m), p2 = expf(l2 - m), p3 = expf(l3 - m);
    const float inv = 1.f / (p0 + p1 + p2 + p3);
    const float w0 = p0 * inv, w1 = p1 * inv, w2 = p2 * inv, w3 = p3 * inv;
    if (t == 0) {
        float4 wv = make_float4(w0, w1, w2, w3);
        *reinterpret_cast<float4*>(rw_out + (size_t)n * 4) = wv;
    }
#pragma unroll
    for (int c = 0; c < 4; ++c) {
        const int idx = c * 1024 + t * 4;
        float4 i0 = *reinterpret_cast<const float4*>(ics + 0 * H_DIM + idx);
        float4 i1 = *reinterpret_cast<const float4*>(ics + 1 * H_DIM + idx);
        float4 i2 = *reinterpret_cast<const float4*>(ics + 2 * H_DIM + idx);
        float4 i3 = *reinterpret_cast<const float4*>(ics + 3 * H_DIM + idx);
        const float sx = w0 * i0.x + w1 * i1.x + w2 * i2.x + w3 * i3.x;
        const float sy = w0 * i0.y + w1 * i1.y + w2 * i2.y + w3 * i3.y;
        const float sz = w0 * i0.z + w1 * i1.z + w2 * i2.z + w3 * i3.z;
        const float sw = w0 * i0.w + w1 * i1.w + w2 * i2.w + w3 * i3.w;
        ushort4 o;
        o.x = f32_bf16_rne(xv[c].x * sx);
        o.y = f32_bf16_rne(xv[c].y * sy);
        o.z = f32_bf16_rne(xv[c].z * sz);
        o.w = f32_bf16_rne(xv[c].w * sw);
        *reinterpret_cast<ushort4*>(xs_out + (size_t)n * H_DIM + idx) = o;
    }
}

// ---------------------------------------------------------------------------
// Kernel 3: C = (xs @ bw^T) * (rw @ ocs) + bias  — 2 blocks/CU for inter-block
// pipe overlap (m114 mechanism: independent blocks have independent barriers,
// so one block's MFMA cluster fills the matrix pipe while the other block is
// in its read/stage/barrier region; intra-block anti-phase is impossible
// because cross-wave staging requires per-window barriers).
//
// 128x256 tile, 4 waves (each 128x64 — wave-level code identical to before),
// BK=32, 3-slot LDS ring = 72 KiB -> 2 blocks/CU (144 KiB), 16 waves/CU.
// LDS map: A slot s @ s*8192 (128 rows x 64 B); B slot s @ 24576 + s*16384
//   (256 rows x 64 B). Swizzle (proven, conflicts=0): logical (row, 16B chunk
//   c) at physical chunk c ^ ((row>>1)&3), on pre-swizzled global source and
//   LDS read; gload_lds dest stays linear.
//
// Ledger (6 gload calls/window/wave: A 2 lines + B 4 lines; read-current,
// stage-2-ahead):
//   prologue: stage T0->s0, T1->s1 (12 calls); vmcnt(6) retires T0; barrier.
//   window W: stage T(W+2) -> slot (W+2)%3   [slot held T(W-1), last read at
//               window W-1; reads complete before W-1's end barrier since
//               every read is consumed by an MFMA issued before the barrier]
//             reads T(W) from slot W%3      [certified: own vmcnt(6) at W-1
//               retired T(W)'s batch + end-W-1 barrier made it block-wide]
//             32 MFMA; vmcnt(6) [retires T(W+1)]; barrier.
//   tail: W=126 no stage, vmcnt(0) (drain T127), barrier; W=127 reads only.
//   Steady loop unrolled x3 so slot indices are compile-time.
// ---------------------------------------------------------------------------

#define STAGE_T(SS, KT)                                                         \
  { _Pragma("unroll")                                                           \
    for (int j = 0; j < 2; ++j)                                                 \
      gload_lds16(gA + ((size_t)j * 64) * H_DIM + (KT) * 32,                    \
                  (unsigned short*)(lds + (SS) * 8192 + j * 4096 + wv * 1024)); \
    _Pragma("unroll")                                                           \
    for (int j = 0; j < 4; ++j)                                                 \
      gload_lds16(gB + ((size_t)j * 64) * H_DIM + (KT) * 32,                    \
                  (unsigned short*)(lds + 24576 + (SS) * 16384 + j * 4096 + wv * 1024)); }

#define GATE6 asm volatile("s_waitcnt vmcnt(6)" ::: "memory")
#define GATE0 asm volatile("s_waitcnt vmcnt(0)" ::: "memory")
#define NOGATE

#define WIN(W, RS, SS, DO_STAGE, GATE_STMT, DO_BAR)                             \
  {                                                                             \
    if (DO_STAGE) STAGE_T(SS, (W) + 2);                                         \
    __builtin_amdgcn_sched_barrier(0);                                          \
    bf16x8 av[8], bv[4];                                                        \
    _Pragma("unroll")                                                           \
    for (int ni = 0; ni < 4; ++ni)                                              \
      bv[ni] = *reinterpret_cast<const bf16x8*>(lds + 24576 + (RS) * 16384 + bOff[ni]); \
    _Pragma("unroll")                                                           \
    for (int fr = 0; fr < 8; ++fr)                                              \
      av[fr] = *reinterpret_cast<const bf16x8*>(lds + (RS) * 8192 + aOff[fr]);  \
    __builtin_amdgcn_s_setprio(1);                                              \
    _Pragma("unroll")                                                           \
    for (int fr = 0; fr < 8; ++fr)                                              \
      _Pragma("unroll")                                                         \
      for (int ni = 0; ni < 4; ++ni)                                            \
        acc[fr][ni] = __builtin_amdgcn_mfma_f32_16x16x32_bf16(av[fr], bv[ni],   \
                                                              acc[fr][ni], 0, 0, 0); \
    __builtin_amdgcn_s_setprio(0);                                              \
    GATE_STMT;                                                                  \
    if (DO_BAR) __builtin_amdgcn_s_barrier();                                   \
  }

__global__ void __launch_bounds__(256, 2) gemm_bin_kernel(
    const unsigned short* __restrict__ xs,   // [N_ROWS][H] bf16
    const unsigned short* __restrict__ bw,   // [O][H] bf16 (row = output col)
    const float* __restrict__ rw,            // [N_ROWS][4]
    const float* __restrict__ ocs,           // [4][O]
    const float* __restrict__ bias,          // [O]
    float* __restrict__ out)                 // [N_ROWS][O]
{
    __shared__ __align__(16) char lds[73728];   // 3*(8K A + 16K B) = 72 KiB

    const int t  = threadIdx.x;
    const int wv = t >> 6;          // 0..3 -> 64-col quarter (all waves: rows 0-127)
    const int ln = t & 63;

    // T1: bijective XCD swizzle (1024 blocks, 1024%8==0)
    const int bid = blockIdx.x;
    const int swz = (bid & 7) * 128 + (bid >> 3);
    const int rowBase = (swz >> 4) * 128;    // 64 M-tiles
    const int colBase = (swz & 15) * 256;    // 16 N-tiles

    // staging thread map: line j covers rows j*64 + (t>>2); physical chunk t&3
    // holds logical chunk (t&3)^((t>>3)&3)  [= (t&3)^((row>>1)&3); j*64 is 0 mod 8]
    const int s_r  = t >> 2;
    const int s_cl = (t & 3) ^ ((t >> 3) & 3);
    const unsigned short* gA = xs + (size_t)(rowBase + s_r) * H_DIM + s_cl * 8;
    const unsigned short* gB = bw + (size_t)(colBase + s_r) * H_DIM + s_cl * 8;

    // read-side fragment byte offsets within a slot (loop-invariant)
    int aOff[8], bOff[4];
#pragma unroll
    for (int fr = 0; fr < 8; ++fr) {
        const int row = fr * 16 + (ln & 15);
        aOff[fr] = row * 64 + (((ln >> 4) ^ ((row >> 1) & 3)) << 4);
    }
#pragma unroll
    for (int ni = 0; ni < 4; ++ni) {
        const int row = wv * 64 + ni * 16 + (ln & 15);
        bOff[ni] = row * 64 + (((ln >> 4) ^ ((row >> 1) & 3)) << 4);
    }

    f32x4 acc[8][4];
#pragma unroll
    for (int i = 0; i < 8; ++i)
#pragma unroll
        for (int j = 0; j < 4; ++j) acc[i][j] = (f32x4){0.f, 0.f, 0.f, 0.f};

    // ---- prologue: stage T0 -> slot0, T1 -> slot1 ----
    STAGE_T(0, 0);
    STAGE_T(1, 1);
    GATE6;                               // retires T0 (T1 flying)
    __builtin_amdgcn_s_barrier();        // T0 certified block-wide

    // ---- main loop: windows 0..125 steady (x3 unroll for const slots) ----
    for (int w = 0; w < 126; w += 3) {
        WIN(w,     0, 2, 1, GATE6, 1);
        WIN(w + 1, 1, 0, 1, GATE6, 1);
        WIN(w + 2, 2, 1, 1, GATE6, 1);
    }
    WIN(126, 0, 0, 0, GATE0, 1);         // drain T127, certify for W=127
    WIN(127, 1, 0, 0, NOGATE, 0);

    // ---- epilogue: y = acc * (rw . ocs[:,col]) + bias ----
    float oce[4][4], bve[4];
    int cole[4];
#pragma unroll
    for (int ni = 0; ni < 4; ++ni) {
        const int col = colBase + wv * 64 + ni * 16 + (ln & 15);
        cole[ni] = col;
        oce[ni][0] = ocs[0 * O_DIM + col];
        oce[ni][1] = ocs[1 * O_DIM + col];
        oce[ni][2] = ocs[2 * O_DIM + col];
        oce[ni][3] = ocs[3 * O_DIM + col];
        bve[ni] = bias[col];
    }
#pragma unroll
    for (int fr = 0; fr < 8; ++fr) {
        float4 rwv[4];
        int rowe[4];
#pragma unroll
        for (int j = 0; j < 4; ++j) {
            const int row = rowBase + fr * 16 + (ln >> 4) * 4 + j;
            rowe[j] = row;
            rwv[j] = *reinterpret_cast<const float4*>(rw + (size_t)row * 4);
        }
#pragma unroll
        for (int ni = 0; ni < 4; ++ni) {
#pragma unroll
            for (int j = 0; j < 4; ++j) {
                const float os = rwv[j].x * oce[ni][0] + rwv[j].y * oce[ni][1] +
                                 rwv[j].z * oce[ni][2] + rwv[j].w * oce[ni][3];
                out[(size_t)rowe[j] * O_DIM + cole[ni]] = acc[fr][ni][j] * os + bve[ni];
            }
        }
    }
}

// ---------------------------------------------------------------------------
extern "C" void kernel_launch(void* const* d_in, const int* in_sizes, int n_in,
                              void* d_out, int out_size, void* d_ws, size_t ws_size,
                              hipStream_t stream) {
    const float* x      = (const float*)d_in[0];
    const float* weight = (const float*)d_in[1];
    const float* bias   = (const float*)d_in[2];
    const float* gate_w = (const float*)d_in[3];
    const float* ics    = (const float*)d_in[4];
    const float* ocs    = (const float*)d_in[5];
    float* out = (float*)d_out;

    unsigned short* xs = (unsigned short*)d_ws;                      // [N][H] bf16
    unsigned short* bw = xs + (size_t)N_ROWS * H_DIM;                // [O][H] bf16
    float* rw = (float*)(bw + (size_t)O_DIM * H_DIM);                // [N][4]

    sign_kernel<<<(O_DIM * H_DIM) / (256 * 4), 256, 0, stream>>>(weight, bw);
    route_scale_kernel<<<N_ROWS, 256, 0, stream>>>(x, gate_w, ics, rw, xs);
    gemm_bin_kernel<<<(N_ROWS / 128) * (O_DIM / 256), 256, 0, stream>>>(xs, bw, rw, ocs, bias, out);
}

// Round 5
// 333.706 us; speedup vs baseline: 1.0463x; 1.0463x over previous
//
#include <hip/hip_runtime.h>
#include <hip/hip_bf16.h>

// BinaryMoSLinear: B=4, S=2048 -> N=8192 rows; H=O=4096; E=4.
#define H_DIM 4096
#define O_DIM 4096
#define N_ROWS 8192

typedef __bf16 bf16x8 __attribute__((ext_vector_type(8)));
typedef float  f32x16 __attribute__((ext_vector_type(16)));

__device__ __forceinline__ unsigned short f32_bf16_rne(float f) {
    unsigned int u = __builtin_bit_cast(unsigned int, f);
    u += 0x7FFFu + ((u >> 16) & 1u);
    return (unsigned short)(u >> 16);
}

__device__ __forceinline__ void gload_lds16(const unsigned short* g, unsigned short* l) {
    __builtin_amdgcn_global_load_lds((const __attribute__((address_space(1))) void*)g,
                                     (__attribute__((address_space(3))) void*)l,
                                     16, 0, 0);
}

// ---------------------------------------------------------------------------
// Kernel 1: bw = sign(weight) as bf16 (+1.0 / -1.0 / 0.0).
// ---------------------------------------------------------------------------
__global__ void __launch_bounds__(256) sign_kernel(const float* __restrict__ w,
                                                   unsigned short* __restrict__ bw) {
    size_t i = ((size_t)blockIdx.x * 256 + threadIdx.x) * 4;
    float4 v = *reinterpret_cast<const float4*>(w + i);
    ushort4 o;
    o.x = v.x > 0.f ? 0x3F80 : (v.x < 0.f ? 0xBF80 : 0);
    o.y = v.y > 0.f ? 0x3F80 : (v.y < 0.f ? 0xBF80 : 0);
    o.z = v.z > 0.f ? 0x3F80 : (v.z < 0.f ? 0xBF80 : 0);
    o.w = v.w > 0.f ? 0x3F80 : (v.w < 0.f ? 0xBF80 : 0);
    *reinterpret_cast<ushort4*>(bw + i) = o;
}

// ---------------------------------------------------------------------------
// Kernel 2: router softmax -> rw[n][4]; xs = bf16(x * (rw @ in_channel_scale)).
// ---------------------------------------------------------------------------
__global__ void __launch_bounds__(256) route_scale_kernel(
    const float* __restrict__ x, const float* __restrict__ gate_w,
    const float* __restrict__ ics, float* __restrict__ rw_out,
    unsigned short* __restrict__ xs_out)
{
    __shared__ float red[4][4];
    const int n = blockIdx.x;
    const int t = threadIdx.x;
    const float* xr = x + (size_t)n * H_DIM;

    float4 xv[4];
    float lg[4] = {0.f, 0.f, 0.f, 0.f};
#pragma unroll
    for (int c = 0; c < 4; ++c) {
        const int idx = c * 1024 + t * 4;
        xv[c] = *reinterpret_cast<const float4*>(xr + idx);
#pragma unroll
        for (int e = 0; e < 4; ++e) {
            float4 g = *reinterpret_cast<const float4*>(gate_w + e * H_DIM + idx);
            lg[e] += xv[c].x * g.x + xv[c].y * g.y + xv[c].z * g.z + xv[c].w * g.w;
        }
    }
#pragma unroll
    for (int e = 0; e < 4; ++e) {
#pragma unroll
        for (int off = 1; off < 64; off <<= 1)
            lg[e] += __shfl_xor(lg[e], off, 64);
    }
    if ((t & 63) == 0) {
        const int w = t >> 6;
        red[w][0] = lg[0]; red[w][1] = lg[1]; red[w][2] = lg[2]; red[w][3] = lg[3];
    }
    __syncthreads();
    const float l0 = red[0][0] + red[1][0] + red[2][0] + red[3][0];
    const float l1 = red[0][1] + red[1][1] + red[2][1] + red[3][1];
    const float l2 = red[0][2] + red[1][2] + red[2][2] + red[3][2];
    const float l3 = red[0][3] + red[1][3] + red[2][3] + red[3][3];
    const float m  = fmaxf(fmaxf(l0, l1), fmaxf(l2, l3));
    const float p0 = expf(l0 - m), p1 = expf(l1 - m), p2 = expf(l2 - m), p3 = expf(l3 - m);
    const float inv = 1.f / (p0 + p1 + p2 + p3);
    const float w0 = p0 * inv, w1 = p1 * inv, w2 = p2 * inv, w3 = p3 * inv;
    if (t == 0) {
        float4 wv = make_float4(w0, w1, w2, w3);
        *reinterpret_cast<float4*>(rw_out + (size_t)n * 4) = wv;
    }
#pragma unroll
    for (int c = 0; c < 4; ++c) {
        const int idx = c * 1024 + t * 4;
        float4 i0 = *reinterpret_cast<const float4*>(ics + 0 * H_DIM + idx);
        float4 i1 = *reinterpret_cast<const float4*>(ics + 1 * H_DIM + idx);
        float4 i2 = *reinterpret_cast<const float4*>(ics + 2 * H_DIM + idx);
        float4 i3 = *reinterpret_cast<const float4*>(ics + 3 * H_DIM + idx);
        const float sx = w0 * i0.x + w1 * i1.x + w2 * i2.x + w3 * i3.x;
        const float sy = w0 * i0.y + w1 * i1.y + w2 * i2.y + w3 * i3.y;
        const float sz = w0 * i0.z + w1 * i1.z + w2 * i2.z + w3 * i3.z;
        const float sw = w0 * i0.w + w1 * i1.w + w2 * i2.w + w3 * i3.w;
        ushort4 o;
        o.x = f32_bf16_rne(xv[c].x * sx);
        o.y = f32_bf16_rne(xv[c].y * sy);
        o.z = f32_bf16_rne(xv[c].z * sz);
        o.w = f32_bf16_rne(xv[c].w * sw);
        *reinterpret_cast<ushort4*>(xs_out + (size_t)n * H_DIM + idx) = o;
    }
}

// ---------------------------------------------------------------------------
// Kernel 3: C = (xs @ bw^T) * (rw @ ocs) + bias  — R3 structure (best: 243 µs)
// with MFMA shape 32x32x16 (99.8%-of-peak shape, m119: 2495 TF vs 2176 for
// 16x16) to shrink the MFMA floor 1242 -> 1034 cyc/window/SIMD.
//
// 256x256 tile, 8 waves (2Mx4N, wave tile 128x64), BK=32, 4-slot LDS ring
// (128 KiB). Window W: [stage T(W+3)] -> gate vmcnt(4) -> 12 ds_reads of
// T(W+1) into ping-pong reg set -> 16 MFMA_32x32x16 on current set ->
// s_barrier. Ledger identical to R3 (proven, conflicts=0):
//   prologue stages T0,T1,T2; vmcnt(4) retires T0,T1; barrier; preload T0.
//   steady gate vmcnt(4) retires all but this window's 4-call batch.
//   tail: W=124 stages T127; W=125 vmcnt(0); 126/127 no gate.
// Swizzle: logical (row, 16B-chunk c) at physical chunk c ^ ((row>>1)&3),
// applied on pre-swizzled global source and on LDS read (both-sides rule).
// LDS map: A slot s @ s*16384 (256 rows x 64 B); B slot s @ 65536 + s*16384.
//
// 32x32x16 fragment mapping (extension of the verified 16x16x32 mapping):
//   A: lane l holds row (l&31), k = (l>>5)*8 + j   (8 bf16 = 1 ds_read_b128)
//   B: lane l holds col (l&31), k = (l>>5)*8 + j
//   C/D: col = lane&31, row = (reg&3) + 8*(reg>>2) + 4*(lane>>5)  [m74/m101]
// Per wave per window: A frags [mb=0..3][kt=0..1], B frags [nb=0..1][kt=0..1]
// -> 12 ds_reads (same as before), 4x2x2 = 16 MFMA.
// ---------------------------------------------------------------------------

#define GATE4 asm volatile("s_waitcnt vmcnt(4)" ::: "memory")
#define GATE0 asm volatile("s_waitcnt vmcnt(0)" ::: "memory")
#define NOGATE

#define WINDOW(W, CA_, CB_, NA_, NB_, DO_STAGE, GATE_STMT, DO_READS, DO_BAR)    \
  {                                                                             \
    const int w_ = (W);                                                         \
    if (DO_STAGE) {                                                             \
      const int ks_ = w_ + 3;                                                   \
      char* sA_ = lds + (ks_ & 3) * 16384;                                      \
      char* sB_ = lds + 65536 + (ks_ & 3) * 16384;                              \
      _Pragma("unroll")                                                         \
      for (int j = 0; j < 2; ++j) {                                             \
        gload_lds16(gA + ((size_t)j * 128) * H_DIM + ks_ * 32,                  \
                    (unsigned short*)(sA_ + j * 8192 + wv * 1024));             \
        gload_lds16(gB + ((size_t)j * 128) * H_DIM + ks_ * 32,                  \
                    (unsigned short*)(sB_ + j * 8192 + wv * 1024));             \
      }                                                                         \
    }                                                                           \
    GATE_STMT;                                                                  \
    __builtin_amdgcn_sched_barrier(0);                                          \
    if (DO_READS) {                                                             \
      const int sb_ = ((w_ + 1) & 3) * 16384;                                   \
      _Pragma("unroll")                                                         \
      for (int mb = 0; mb < 4; ++mb)                                            \
        _Pragma("unroll")                                                       \
        for (int kt = 0; kt < 2; ++kt)                                          \
          NA_[mb*2+kt] = *reinterpret_cast<const bf16x8*>(lds + sb_ + aOff[mb][kt]); \
      _Pragma("unroll")                                                         \
      for (int nb = 0; nb < 2; ++nb)                                            \
        _Pragma("unroll")                                                       \
        for (int kt = 0; kt < 2; ++kt)                                          \
          NB_[nb*2+kt] = *reinterpret_cast<const bf16x8*>(lds + 65536 + sb_ + bOff[nb][kt]); \
    }                                                                           \
    __builtin_amdgcn_sched_barrier(0);                                          \
    __builtin_amdgcn_s_setprio(1);                                              \
    _Pragma("unroll")                                                           \
    for (int mb = 0; mb < 4; ++mb)                                              \
      _Pragma("unroll")                                                         \
      for (int nb = 0; nb < 2; ++nb)                                            \
        _Pragma("unroll")                                                       \
        for (int kt = 0; kt < 2; ++kt)                                          \
          acc[mb][nb] = __builtin_amdgcn_mfma_f32_32x32x16_bf16(                \
              CA_[mb*2+kt], CB_[nb*2+kt], acc[mb][nb], 0, 0, 0);                \
    __builtin_amdgcn_s_setprio(0);                                              \
    __builtin_amdgcn_sched_barrier(0);                                          \
    if (DO_BAR) __builtin_amdgcn_s_barrier();                                   \
  }

__global__ void __launch_bounds__(512, 2) gemm_bin_kernel(
    const unsigned short* __restrict__ xs,   // [N_ROWS][H] bf16
    const unsigned short* __restrict__ bw,   // [O][H] bf16 (row = output col)
    const float* __restrict__ rw,            // [N_ROWS][4]
    const float* __restrict__ ocs,           // [4][O]
    const float* __restrict__ bias,          // [O]
    float* __restrict__ out)                 // [N_ROWS][O]
{
    __shared__ __align__(16) char lds[131072];

    const int t  = threadIdx.x;
    const int wv = t >> 6;
    const int ln = t & 63;
    const int wr = wv >> 2;          // 0..1 -> 128-row half
    const int wc = wv & 3;           // 0..3 -> 64-col quarter

    // T1: bijective XCD swizzle (512 blocks, 512%8==0)
    const int bid = blockIdx.x;
    const int swz = (bid & 7) * 64 + (bid >> 3);
    const int rowBase = (swz >> 4) * 256;    // 32 M-tiles
    const int colBase = (swz & 15) * 256;    // 16 N-tiles

    // staging thread map: row r = j*128 + (t>>2), physical chunk t&3 holds
    // logical chunk (t&3)^((t>>3)&3)  [= (t&3)^((row>>1)&3)]
    const int s_r  = t >> 2;
    const int s_cl = (t & 3) ^ ((t >> 3) & 3);
    const unsigned short* gA = xs + (size_t)(rowBase + s_r) * H_DIM + s_cl * 8;
    const unsigned short* gB = bw + (size_t)(colBase + s_r) * H_DIM + s_cl * 8;

    // read-side fragment byte offsets within a slot (loop-invariant)
    // A: row = wr*128 + mb*32 + (ln&31), chunk c = (ln>>5) + 2*kt
    // B: row = wc*64  + nb*32 + (ln&31), chunk c = (ln>>5) + 2*kt
    int aOff[4][2], bOff[2][2];
#pragma unroll
    for (int mb = 0; mb < 4; ++mb) {
        const int row = wr * 128 + mb * 32 + (ln & 31);
#pragma unroll
        for (int kt = 0; kt < 2; ++kt) {
            const int c = (ln >> 5) + 2 * kt;
            aOff[mb][kt] = row * 64 + ((c ^ ((row >> 1) & 3)) << 4);
        }
    }
#pragma unroll
    for (int nb = 0; nb < 2; ++nb) {
        const int row = wc * 64 + nb * 32 + (ln & 31);
#pragma unroll
        for (int kt = 0; kt < 2; ++kt) {
            const int c = (ln >> 5) + 2 * kt;
            bOff[nb][kt] = row * 64 + ((c ^ ((row >> 1) & 3)) << 4);
        }
    }

    f32x16 acc[4][2];
#pragma unroll
    for (int i = 0; i < 4; ++i)
#pragma unroll
        for (int j = 0; j < 2; ++j)
            acc[i][j] = (f32x16){0.f,0.f,0.f,0.f,0.f,0.f,0.f,0.f,
                                 0.f,0.f,0.f,0.f,0.f,0.f,0.f,0.f};

    // ---- prologue: stage tiles 0,1,2 (slots 0,1,2) ----
#pragma unroll
    for (int kt = 0; kt < 3; ++kt) {
        char* sA = lds + kt * 16384;
        char* sB = lds + 65536 + kt * 16384;
#pragma unroll
        for (int j = 0; j < 2; ++j) {
            gload_lds16(gA + ((size_t)j * 128) * H_DIM + kt * 32,
                        (unsigned short*)(sA + j * 8192 + wv * 1024));
            gload_lds16(gB + ((size_t)j * 128) * H_DIM + kt * 32,
                        (unsigned short*)(sB + j * 8192 + wv * 1024));
        }
    }
    GATE4;                               // retires T0,T1 (leaves T2 flying)
    __builtin_amdgcn_s_barrier();        // -> T0,T1 certified block-wide

    // preload current register set from tile 0 (slot 0)
    bf16x8 avA[8], bvA[4], avB[8], bvB[4];
#pragma unroll
    for (int mb = 0; mb < 4; ++mb)
#pragma unroll
        for (int kt = 0; kt < 2; ++kt)
            avA[mb*2+kt] = *reinterpret_cast<const bf16x8*>(lds + aOff[mb][kt]);
#pragma unroll
    for (int nb = 0; nb < 2; ++nb)
#pragma unroll
        for (int kt = 0; kt < 2; ++kt)
            bvA[nb*2+kt] = *reinterpret_cast<const bf16x8*>(lds + 65536 + bOff[nb][kt]);

    // ---- main loop: windows 0..123 (steady), 124..127 peeled ----
    for (int w = 0; w < 124; w += 2) {
        WINDOW(w,     avA, bvA, avB, bvB, 1, GATE4, 1, 1);
        WINDOW(w + 1, avB, bvB, avA, bvA, 1, GATE4, 1, 1);
    }
    WINDOW(124, avA, bvA, avB, bvB, 1, GATE4,  1, 1);   // stages T127 (last)
    WINDOW(125, avB, bvB, avA, bvA, 0, GATE0,  1, 1);   // certify T127
    WINDOW(126, avA, bvA, avB, bvB, 0, NOGATE, 1, 1);
    WINDOW(127, avB, bvB, avA, bvA, 0, NOGATE, 0, 0);

    // ---- epilogue: y = acc * (rw . ocs[:,col]) + bias ----
    // C/D: col = lane&31 (per nb), row = mb*32 + 4*(ln>>5) + 8*q + j, reg=q*4+j
    float oce[2][4], bve[2];
    int cole[2];
#pragma unroll
    for (int nb = 0; nb < 2; ++nb) {
        const int col = colBase + wc * 64 + nb * 32 + (ln & 31);
        cole[nb] = col;
        oce[nb][0] = ocs[0 * O_DIM + col];
        oce[nb][1] = ocs[1 * O_DIM + col];
        oce[nb][2] = ocs[2 * O_DIM + col];
        oce[nb][3] = ocs[3 * O_DIM + col];
        bve[nb] = bias[col];
    }
#pragma unroll
    for (int mb = 0; mb < 4; ++mb) {
#pragma unroll
        for (int q = 0; q < 4; ++q) {
#pragma unroll
            for (int j = 0; j < 4; ++j) {
                const int row = rowBase + wr * 128 + mb * 32 + (ln >> 5) * 4 + q * 8 + j;
                const float4 rv = *reinterpret_cast<const float4*>(rw + (size_t)row * 4);
#pragma unroll
                for (int nb = 0; nb < 2; ++nb) {
                    const float os = rv.x * oce[nb][0] + rv.y * oce[nb][1] +
                                     rv.z * oce[nb][2] + rv.w * oce[nb][3];
                    out[(size_t)row * O_DIM + cole[nb]] = acc[mb][nb][q * 4 + j] * os + bve[nb];
                }
            }
        }
    }
}

// ---------------------------------------------------------------------------
extern "C" void kernel_launch(void* const* d_in, const int* in_sizes, int n_in,
                              void* d_out, int out_size, void* d_ws, size_t ws_size,
                              hipStream_t stream) {
    const float* x      = (const float*)d_in[0];
    const float* weight = (const float*)d_in[1];
    const float* bias   = (const float*)d_in[2];
    const float* gate_w = (const float*)d_in[3];
    const float* ics    = (const float*)d_in[4];
    const float* ocs    = (const float*)d_in[5];
    float* out = (float*)d_out;

    unsigned short* xs = (unsigned short*)d_ws;                      // [N][H] bf16
    unsigned short* bw = xs + (size_t)N_ROWS * H_DIM;                // [O][H] bf16
    float* rw = (float*)(bw + (size_t)O_DIM * H_DIM);                // [N][4]

    sign_kernel<<<(O_DIM * H_DIM) / (256 * 4), 256, 0, stream>>>(weight, bw);
    route_scale_kernel<<<N_ROWS, 256, 0, stream>>>(x, gate_w, ics, rw, xs);
    gemm_bin_kernel<<<(N_ROWS / 256) * (O_DIM / 256), 512, 0, stream>>>(xs, bw, rw, ocs, bias, out);
}

// Round 6
// 333.404 us; speedup vs baseline: 1.0472x; 1.0009x over previous
//
#include <hip/hip_runtime.h>
#include <hip/hip_bf16.h>

// BinaryMoSLinear: B=4, S=2048 -> N=8192 rows; H=O=4096; E=4.
#define H_DIM 4096
#define O_DIM 4096
#define N_ROWS 8192

typedef __bf16 bf16x8 __attribute__((ext_vector_type(8)));
typedef float  f32x16 __attribute__((ext_vector_type(16)));

__device__ __forceinline__ unsigned short f32_bf16_rne(float f) {
    unsigned int u = __builtin_bit_cast(unsigned int, f);
    u += 0x7FFFu + ((u >> 16) & 1u);
    return (unsigned short)(u >> 16);
}

__device__ __forceinline__ void gload_lds16(const unsigned short* g, unsigned short* l) {
    __builtin_amdgcn_global_load_lds((const __attribute__((address_space(1))) void*)g,
                                     (__attribute__((address_space(3))) void*)l,
                                     16, 0, 0);
}

// ---------------------------------------------------------------------------
// Kernel 1: bw = sign(weight) as bf16 (+1.0 / -1.0 / 0.0).
// ---------------------------------------------------------------------------
__global__ void __launch_bounds__(256) sign_kernel(const float* __restrict__ w,
                                                   unsigned short* __restrict__ bw) {
    size_t i = ((size_t)blockIdx.x * 256 + threadIdx.x) * 4;
    float4 v = *reinterpret_cast<const float4*>(w + i);
    ushort4 o;
    o.x = v.x > 0.f ? 0x3F80 : (v.x < 0.f ? 0xBF80 : 0);
    o.y = v.y > 0.f ? 0x3F80 : (v.y < 0.f ? 0xBF80 : 0);
    o.z = v.z > 0.f ? 0x3F80 : (v.z < 0.f ? 0xBF80 : 0);
    o.w = v.w > 0.f ? 0x3F80 : (v.w < 0.f ? 0xBF80 : 0);
    *reinterpret_cast<ushort4*>(bw + i) = o;
}

// ---------------------------------------------------------------------------
// Kernel 2: router softmax -> rw[n][4]; xs = bf16(x * (rw @ in_channel_scale)).
// ---------------------------------------------------------------------------
__global__ void __launch_bounds__(256) route_scale_kernel(
    const float* __restrict__ x, const float* __restrict__ gate_w,
    const float* __restrict__ ics, float* __restrict__ rw_out,
    unsigned short* __restrict__ xs_out)
{
    __shared__ float red[4][4];
    const int n = blockIdx.x;
    const int t = threadIdx.x;
    const float* xr = x + (size_t)n * H_DIM;

    float4 xv[4];
    float lg[4] = {0.f, 0.f, 0.f, 0.f};
#pragma unroll
    for (int c = 0; c < 4; ++c) {
        const int idx = c * 1024 + t * 4;
        xv[c] = *reinterpret_cast<const float4*>(xr + idx);
#pragma unroll
        for (int e = 0; e < 4; ++e) {
            float4 g = *reinterpret_cast<const float4*>(gate_w + e * H_DIM + idx);
            lg[e] += xv[c].x * g.x + xv[c].y * g.y + xv[c].z * g.z + xv[c].w * g.w;
        }
    }
#pragma unroll
    for (int e = 0; e < 4; ++e) {
#pragma unroll
        for (int off = 1; off < 64; off <<= 1)
            lg[e] += __shfl_xor(lg[e], off, 64);
    }
    if ((t & 63) == 0) {
        const int w = t >> 6;
        red[w][0] = lg[0]; red[w][1] = lg[1]; red[w][2] = lg[2]; red[w][3] = lg[3];
    }
    __syncthreads();
    const float l0 = red[0][0] + red[1][0] + red[2][0] + red[3][0];
    const float l1 = red[0][1] + red[1][1] + red[2][1] + red[3][1];
    const float l2 = red[0][2] + red[1][2] + red[2][2] + red[3][2];
    const float l3 = red[0][3] + red[1][3] + red[2][3] + red[3][3];
    const float m  = fmaxf(fmaxf(l0, l1), fmaxf(l2, l3));
    const float p0 = expf(l0 - m), p1 = expf(l1 - m), p2 = expf(l2 - m), p3 = expf(l3 - m);
    const float inv = 1.f / (p0 + p1 + p2 + p3);
    const float w0 = p0 * inv, w1 = p1 * inv, w2 = p2 * inv, w3 = p3 * inv;
    if (t == 0) {
        float4 wv = make_float4(w0, w1, w2, w3);
        *reinterpret_cast<float4*>(rw_out + (size_t)n * 4) = wv;
    }
#pragma unroll
    for (int c = 0; c < 4; ++c) {
        const int idx = c * 1024 + t * 4;
        float4 i0 = *reinterpret_cast<const float4*>(ics + 0 * H_DIM + idx);
        float4 i1 = *reinterpret_cast<const float4*>(ics + 1 * H_DIM + idx);
        float4 i2 = *reinterpret_cast<const float4*>(ics + 2 * H_DIM + idx);
        float4 i3 = *reinterpret_cast<const float4*>(ics + 3 * H_DIM + idx);
        const float sx = w0 * i0.x + w1 * i1.x + w2 * i2.x + w3 * i3.x;
        const float sy = w0 * i0.y + w1 * i1.y + w2 * i2.y + w3 * i3.y;
        const float sz = w0 * i0.z + w1 * i1.z + w2 * i2.z + w3 * i3.z;
        const float sw = w0 * i0.w + w1 * i1.w + w2 * i2.w + w3 * i3.w;
        ushort4 o;
        o.x = f32_bf16_rne(xv[c].x * sx);
        o.y = f32_bf16_rne(xv[c].y * sy);
        o.z = f32_bf16_rne(xv[c].z * sz);
        o.w = f32_bf16_rne(xv[c].w * sw);
        *reinterpret_cast<ushort4*>(xs_out + (size_t)n * H_DIM + idx) = o;
    }
}

// ---------------------------------------------------------------------------
// Kernel 3: C = (xs @ bw^T) * (rw @ ocs) + bias  — R5 structure with the
// bank-conflict fix for the 32x32x16 read pattern.
//
// Why R5 conflicted (2.5e7): each 32x32 ds_read uses logical chunks {0,1}
// only (c = ln>>5; kt selects +2 in a separate instruction). XOR swizzle
// maps the PAIR {0,1} to {0,1} or {2,3} wholesale -> rows 0..3 at c=0 all
// hit the same 8-bank group (4-way). Fix: mod-4 ADDITIVE rotation
//   phys = (c + s) & 3,  s = (row>>1)&3
// -> even rows 0,2,4,6 at fixed c get phys 0,1,2,3 (full 16B-group spread).
// Rows r/r+8 remain 2-way aliased — present in the proven-0-conflict 16x16
// pattern too; 2-way is free (m136).
// Both-sides rule: staging source fetches logical (p - s)&3 into physical
// chunk p (gload_lds dest linear); reads apply (c + s)&3.
//
// Everything else identical to R5: 256x256 tile, 8 waves (2Mx4N, wave tile
// 128x64), BK=32, 4-slot LDS ring (128 KiB), mfma_f32_32x32x16_bf16
// (99.8%-of-peak shape), R3 ledger (stage T(W+3), gate vmcnt(4), ping-pong
// reg sets, per-window barrier).
// 32x32x16 fragments: A/B lane l: row/col (l&31), k = (l>>5)*8 + j;
// C/D: col = lane&31, row = (reg&3) + 8*(reg>>2) + 4*(lane>>5)  [m74/m101].
// ---------------------------------------------------------------------------

#define GATE4 asm volatile("s_waitcnt vmcnt(4)" ::: "memory")
#define GATE0 asm volatile("s_waitcnt vmcnt(0)" ::: "memory")
#define NOGATE

#define WINDOW(W, CA_, CB_, NA_, NB_, DO_STAGE, GATE_STMT, DO_READS, DO_BAR)    \
  {                                                                             \
    const int w_ = (W);                                                         \
    if (DO_STAGE) {                                                             \
      const int ks_ = w_ + 3;                                                   \
      char* sA_ = lds + (ks_ & 3) * 16384;                                      \
      char* sB_ = lds + 65536 + (ks_ & 3) * 16384;                              \
      _Pragma("unroll")                                                         \
      for (int j = 0; j < 2; ++j) {                                             \
        gload_lds16(gA + ((size_t)j * 128) * H_DIM + ks_ * 32,                  \
                    (unsigned short*)(sA_ + j * 8192 + wv * 1024));             \
        gload_lds16(gB + ((size_t)j * 128) * H_DIM + ks_ * 32,                  \
                    (unsigned short*)(sB_ + j * 8192 + wv * 1024));             \
      }                                                                         \
    }                                                                           \
    GATE_STMT;                                                                  \
    __builtin_amdgcn_sched_barrier(0);                                          \
    if (DO_READS) {                                                             \
      const int sb_ = ((w_ + 1) & 3) * 16384;                                   \
      _Pragma("unroll")                                                         \
      for (int mb = 0; mb < 4; ++mb)                                            \
        _Pragma("unroll")                                                       \
        for (int kt = 0; kt < 2; ++kt)                                          \
          NA_[mb*2+kt] = *reinterpret_cast<const bf16x8*>(lds + sb_ + aOff[mb][kt]); \
      _Pragma("unroll")                                                         \
      for (int nb = 0; nb < 2; ++nb)                                            \
        _Pragma("unroll")                                                       \
        for (int kt = 0; kt < 2; ++kt)                                          \
          NB_[nb*2+kt] = *reinterpret_cast<const bf16x8*>(lds + 65536 + sb_ + bOff[nb][kt]); \
    }                                                                           \
    __builtin_amdgcn_sched_barrier(0);                                          \
    __builtin_amdgcn_s_setprio(1);                                              \
    _Pragma("unroll")                                                           \
    for (int mb = 0; mb < 4; ++mb)                                              \
      _Pragma("unroll")                                                         \
      for (int nb = 0; nb < 2; ++nb)                                            \
        _Pragma("unroll")                                                       \
        for (int kt = 0; kt < 2; ++kt)                                          \
          acc[mb][nb] = __builtin_amdgcn_mfma_f32_32x32x16_bf16(                \
              CA_[mb*2+kt], CB_[nb*2+kt], acc[mb][nb], 0, 0, 0);                \
    __builtin_amdgcn_s_setprio(0);                                              \
    __builtin_amdgcn_sched_barrier(0);                                          \
    if (DO_BAR) __builtin_amdgcn_s_barrier();                                   \
  }

__global__ void __launch_bounds__(512, 2) gemm_bin_kernel(
    const unsigned short* __restrict__ xs,   // [N_ROWS][H] bf16
    const unsigned short* __restrict__ bw,   // [O][H] bf16 (row = output col)
    const float* __restrict__ rw,            // [N_ROWS][4]
    const float* __restrict__ ocs,           // [4][O]
    const float* __restrict__ bias,          // [O]
    float* __restrict__ out)                 // [N_ROWS][O]
{
    __shared__ __align__(16) char lds[131072];

    const int t  = threadIdx.x;
    const int wv = t >> 6;
    const int ln = t & 63;
    const int wr = wv >> 2;          // 0..1 -> 128-row half
    const int wc = wv & 3;           // 0..3 -> 64-col quarter

    // T1: bijective XCD swizzle (512 blocks, 512%8==0)
    const int bid = blockIdx.x;
    const int swz = (bid & 7) * 64 + (bid >> 3);
    const int rowBase = (swz >> 4) * 256;    // 32 M-tiles
    const int colBase = (swz & 15) * 256;    // 16 N-tiles

    // staging thread map: row r = t>>2 (stride 128 for line j); physical chunk
    // p = t&3 receives logical chunk (p - s)&3, s = ((r>>1)&3) = ((t>>3)&3)
    const int s_r  = t >> 2;
    const int s_cl = ((t & 3) - ((t >> 3) & 3)) & 3;
    const unsigned short* gA = xs + (size_t)(rowBase + s_r) * H_DIM + s_cl * 8;
    const unsigned short* gB = bw + (size_t)(colBase + s_r) * H_DIM + s_cl * 8;

    // read-side fragment byte offsets within a slot (loop-invariant)
    // A: row = wr*128 + mb*32 + (ln&31), logical chunk c = (ln>>5) + 2*kt
    // B: row = wc*64  + nb*32 + (ln&31), same c; phys = (c + (row>>1)&3) & 3
    int aOff[4][2], bOff[2][2];
#pragma unroll
    for (int mb = 0; mb < 4; ++mb) {
        const int row = wr * 128 + mb * 32 + (ln & 31);
#pragma unroll
        for (int kt = 0; kt < 2; ++kt) {
            const int c = (ln >> 5) + 2 * kt;
            aOff[mb][kt] = row * 64 + (((c + ((row >> 1) & 3)) & 3) << 4);
        }
    }
#pragma unroll
    for (int nb = 0; nb < 2; ++nb) {
        const int row = wc * 64 + nb * 32 + (ln & 31);
#pragma unroll
        for (int kt = 0; kt < 2; ++kt) {
            const int c = (ln >> 5) + 2 * kt;
            bOff[nb][kt] = row * 64 + (((c + ((row >> 1) & 3)) & 3) << 4);
        }
    }

    f32x16 acc[4][2];
#pragma unroll
    for (int i = 0; i < 4; ++i)
#pragma unroll
        for (int j = 0; j < 2; ++j)
            acc[i][j] = (f32x16){0.f,0.f,0.f,0.f,0.f,0.f,0.f,0.f,
                                 0.f,0.f,0.f,0.f,0.f,0.f,0.f,0.f};

    // ---- prologue: stage tiles 0,1,2 (slots 0,1,2) ----
#pragma unroll
    for (int kt = 0; kt < 3; ++kt) {
        char* sA = lds + kt * 16384;
        char* sB = lds + 65536 + kt * 16384;
#pragma unroll
        for (int j = 0; j < 2; ++j) {
            gload_lds16(gA + ((size_t)j * 128) * H_DIM + kt * 32,
                        (unsigned short*)(sA + j * 8192 + wv * 1024));
            gload_lds16(gB + ((size_t)j * 128) * H_DIM + kt * 32,
                        (unsigned short*)(sB + j * 8192 + wv * 1024));
        }
    }
    GATE4;                               // retires T0,T1 (leaves T2 flying)
    __builtin_amdgcn_s_barrier();        // -> T0,T1 certified block-wide

    // preload current register set from tile 0 (slot 0)
    bf16x8 avA[8], bvA[4], avB[8], bvB[4];
#pragma unroll
    for (int mb = 0; mb < 4; ++mb)
#pragma unroll
        for (int kt = 0; kt < 2; ++kt)
            avA[mb*2+kt] = *reinterpret_cast<const bf16x8*>(lds + aOff[mb][kt]);
#pragma unroll
    for (int nb = 0; nb < 2; ++nb)
#pragma unroll
        for (int kt = 0; kt < 2; ++kt)
            bvA[nb*2+kt] = *reinterpret_cast<const bf16x8*>(lds + 65536 + bOff[nb][kt]);

    // ---- main loop: windows 0..123 (steady), 124..127 peeled ----
    for (int w = 0; w < 124; w += 2) {
        WINDOW(w,     avA, bvA, avB, bvB, 1, GATE4, 1, 1);
        WINDOW(w + 1, avB, bvB, avA, bvA, 1, GATE4, 1, 1);
    }
    WINDOW(124, avA, bvA, avB, bvB, 1, GATE4,  1, 1);   // stages T127 (last)
    WINDOW(125, avB, bvB, avA, bvA, 0, GATE0,  1, 1);   // certify T127
    WINDOW(126, avA, bvA, avB, bvB, 0, NOGATE, 1, 1);
    WINDOW(127, avB, bvB, avA, bvA, 0, NOGATE, 0, 0);

    // ---- epilogue: y = acc * (rw . ocs[:,col]) + bias ----
    // C/D: col = lane&31 (per nb), row = mb*32 + 4*(ln>>5) + 8*q + j, reg=q*4+j
    float oce[2][4], bve[2];
    int cole[2];
#pragma unroll
    for (int nb = 0; nb < 2; ++nb) {
        const int col = colBase + wc * 64 + nb * 32 + (ln & 31);
        cole[nb] = col;
        oce[nb][0] = ocs[0 * O_DIM + col];
        oce[nb][1] = ocs[1 * O_DIM + col];
        oce[nb][2] = ocs[2 * O_DIM + col];
        oce[nb][3] = ocs[3 * O_DIM + col];
        bve[nb] = bias[col];
    }
#pragma unroll
    for (int mb = 0; mb < 4; ++mb) {
#pragma unroll
        for (int q = 0; q < 4; ++q) {
#pragma unroll
            for (int j = 0; j < 4; ++j) {
                const int row = rowBase + wr * 128 + mb * 32 + (ln >> 5) * 4 + q * 8 + j;
                const float4 rv = *reinterpret_cast<const float4*>(rw + (size_t)row * 4);
#pragma unroll
                for (int nb = 0; nb < 2; ++nb) {
                    const float os = rv.x * oce[nb][0] + rv.y * oce[nb][1] +
                                     rv.z * oce[nb][2] + rv.w * oce[nb][3];
                    out[(size_t)row * O_DIM + cole[nb]] = acc[mb][nb][q * 4 + j] * os + bve[nb];
                }
            }
        }
    }
}

// ---------------------------------------------------------------------------
extern "C" void kernel_launch(void* const* d_in, const int* in_sizes, int n_in,
                              void* d_out, int out_size, void* d_ws, size_t ws_size,
                              hipStream_t stream) {
    const float* x      = (const float*)d_in[0];
    const float* weight = (const float*)d_in[1];
    const float* bias   = (const float*)d_in[2];
    const float* gate_w = (const float*)d_in[3];
    const float* ics    = (const float*)d_in[4];
    const float* ocs    = (const float*)d_in[5];
    float* out = (float*)d_out;

    unsigned short* xs = (unsigned short*)d_ws;                      // [N][H] bf16
    unsigned short* bw = xs + (size_t)N_ROWS * H_DIM;                // [O][H] bf16
    float* rw = (float*)(bw + (size_t)O_DIM * H_DIM);                // [N][4]

    sign_kernel<<<(O_DIM * H_DIM) / (256 * 4), 256, 0, stream>>>(weight, bw);
    route_scale_kernel<<<N_ROWS, 256, 0, stream>>>(x, gate_w, ics, rw, xs);
    gemm_bin_kernel<<<(N_ROWS / 256) * (O_DIM / 256), 512, 0, stream>>>(xs, bw, rw, ocs, bias, out);
}